// Round 1
// baseline (41.111 us; speedup 1.0000x reference)
//
#include <hip/hip_runtime.h>

// Box filter, kernel 1024x1024 constant, reflect pad (pl=pt=511, pr=pb=512).
// Separable: per-line windowed sum over reflect-padded line of length 2047
// decomposes into <=3 contiguous ranges of the original line, each a
// difference of exclusive prefix sums S (S[i] = sum of line[0..i-1]).

static constexpr float KC = 2.5652997311834374e-21f;

__device__ __forceinline__ float window_sum(const float* S, int o, int stride) {
    float r = 0.f;
    // left mirror segment: padded px in [o, 511) -> orig [1, 511-o]
    if (o <= 510) r += S[(512 - o) * stride] - S[stride];
    // main segment: padded px in [max(o,511), min(o+1024,1535)) -> orig [b0, b1)
    const int b0 = o > 511 ? o - 511 : 0;
    const int b1 = o + 513 < 1024 ? o + 513 : 1024;
    r += S[b1 * stride] - S[b0 * stride];
    // right mirror segment: padded px in [1535, o+1024) -> orig [1534-o, 1022]
    if (o >= 512) r += S[1023 * stride] - S[(1534 - o) * stride];
    return r;
}

// Pass 1: horizontal window sums. One block (256 threads) per image row.
__global__ __launch_bounds__(256) void hpass_kernel(const float* __restrict__ x,
                                                    float* __restrict__ T) {
    __shared__ float S[1025];   // exclusive prefix of the row
    __shared__ float wtot[4];
    const int t = threadIdx.x;
    const size_t rowbase = (size_t)blockIdx.x * 1024;
    const float4 v = reinterpret_cast<const float4*>(x + rowbase)[t];
    const float p0 = v.x, p1 = p0 + v.y, p2 = p1 + v.z, p3 = p2 + v.w;
    const int lane = t & 63, wave = t >> 6;
    // wave-level inclusive scan of per-thread sums (p3)
    float inc = p3;
    #pragma unroll
    for (int off = 1; off < 64; off <<= 1) {
        float n = __shfl_up(inc, off);
        if (lane >= off) inc += n;
    }
    if (lane == 63) wtot[wave] = inc;
    __syncthreads();
    float woff = 0.f;
    for (int w = 0; w < wave; ++w) woff += wtot[w];
    const float excl = woff + inc - p3;    // exclusive prefix at element 4t
    S[4 * t + 0] = excl;
    S[4 * t + 1] = excl + p0;
    S[4 * t + 2] = excl + p1;
    S[4 * t + 3] = excl + p2;
    if (t == 255) S[1024] = excl + p3;
    __syncthreads();
    float4 o;
    const int ox = 4 * t;
    o.x = window_sum(S, ox + 0, 1);
    o.y = window_sum(S, ox + 1, 1);
    o.z = window_sum(S, ox + 2, 1);
    o.w = window_sum(S, ox + 3, 1);
    reinterpret_cast<float4*>(T + rowbase)[t] = o;
}

// Pass 2: vertical window sums, in place on T (= d_out).
// One block per (channel, 16-column tile); tile fully staged in LDS before
// any write, so in-place is safe.
__global__ __launch_bounds__(256) void vpass_kernel(float* __restrict__ T) {
    constexpr int NC = 16, STR = 17;   // stride 17 breaks bank conflicts
    __shared__ float P[1025 * STR];    // P[y*STR+c] -> exclusive column prefix
    __shared__ float part[16 * NC];
    const int t = threadIdx.x;
    const int ch = blockIdx.x >> 6;           // 64 tiles per channel
    const int col0 = (blockIdx.x & 63) * NC;
    float* base = T + (size_t)ch * 1024 * 1024 + col0;
    const int c = t & 15, yt = t >> 4;        // yt in [0,16)

    // load tile: row y value goes to P[(y+1)*STR + c]
    for (int y = yt; y < 1024; y += 16)
        P[(y + 1) * STR + c] = base[(size_t)y * 1024 + c];
    if (t < NC) P[t] = 0.f;                   // P[0] = 0
    __syncthreads();

    // two-level column scan: 16 threads per column, 64 rows each
    const int y0 = yt * 64;
    float s = 0.f;
    for (int r = 0; r < 64; ++r) s += P[(y0 + 1 + r) * STR + c];
    part[yt * NC + c] = s;
    __syncthreads();
    float run = 0.f;
    for (int sg = 0; sg < yt; ++sg) run += part[sg * NC + c];
    for (int r = 0; r < 64; ++r) {
        const int idx = (y0 + 1 + r) * STR + c;
        run += P[idx];
        P[idx] = run;                          // in-place inclusive -> P[y] = sum rows [0,y)
    }
    __syncthreads();

    const float* Sc = &P[c];
    for (int oy = yt; oy < 1024; oy += 16)
        base[(size_t)oy * 1024 + c] = KC * window_sum(Sc, oy, STR);
}

extern "C" void kernel_launch(void* const* d_in, const int* in_sizes, int n_in,
                              void* d_out, int out_size, void* d_ws, size_t ws_size,
                              hipStream_t stream) {
    // inputs: [0]=H(int), [1]=W(int), [2]=x(f32, 2x3x1024x1024), [3]=Kh, [4]=Kw
    const float* x = (const float*)d_in[2];
    float* out = (float*)d_out;
    hpass_kernel<<<2 * 3 * 1024, 256, 0, stream>>>(x, out);   // T -> d_out
    vpass_kernel<<<6 * 64, 256, 0, stream>>>(out);            // in-place vertical
}